// Round 1
// baseline (4225.530 us; speedup 1.0000x reference)
//
#include <hip/hip_runtime.h>
#include <math.h>

#define Bc 2
#define Sc 2048
#define Dc 1024
#define Hc 16
#define HDc 64
#define NROWS 4096  // B*S

// ---------------------------------------------------------------------------
// GEMM: C = (A @ W^T + bias) * alpha
//   A: [4096, 1024] row-major, W: [1024, 1024] row-major [out,in]
//   mode 0: head-split write -> out0 laid out as [B,H,S,HD]
//   mode 1: out1[i*D+o] = v (gated); out0[i*D+o] = feats[i*D+o] * v (out)
// ---------------------------------------------------------------------------
__global__ __launch_bounds__(256)
void gemm_kernel(const float* __restrict__ A, const float* __restrict__ W,
                 const float* __restrict__ bias, float alpha,
                 float* __restrict__ out0, float* __restrict__ out1,
                 const float* __restrict__ feats, int mode)
{
  __shared__ float As[64][17];
  __shared__ float Ws[64][17];
  const int tid = threadIdx.x;
  const int tx = tid & 15, ty = tid >> 4;
  const int row0 = blockIdx.x * 64, col0 = blockIdx.y * 64;
  float acc[4][4] = {{0.f}};

  for (int k0 = 0; k0 < Dc; k0 += 16) {
#pragma unroll
    for (int j = 0; j < 4; ++j) {
      int e = tid + 256 * j;
      int r = e >> 4, c = e & 15;
      As[r][c] = A[(size_t)(row0 + r) * Dc + k0 + c];
      Ws[r][c] = W[(size_t)(col0 + r) * Dc + k0 + c];
    }
    __syncthreads();
#pragma unroll
    for (int kk = 0; kk < 16; ++kk) {
      float a[4], w[4];
#pragma unroll
      for (int m = 0; m < 4; ++m) a[m] = As[ty * 4 + m][kk];
#pragma unroll
      for (int n = 0; n < 4; ++n) w[n] = Ws[tx * 4 + n][kk];
#pragma unroll
      for (int m = 0; m < 4; ++m)
#pragma unroll
        for (int n = 0; n < 4; ++n) acc[m][n] += a[m] * w[n];
    }
    __syncthreads();
  }

#pragma unroll
  for (int m = 0; m < 4; ++m) {
#pragma unroll
    for (int n = 0; n < 4; ++n) {
      int i = row0 + ty * 4 + m;
      int o = col0 + tx * 4 + n;
      float val = (acc[m][n] + bias[o]) * alpha;
      if (mode == 0) {
        int b = i >> 11, s = i & (Sc - 1);
        int h = o >> 6, hd = o & 63;
        out0[((((size_t)b * Hc + h) * Sc) + s) * HDc + hd] = val;
      } else {
        out1[(size_t)i * Dc + o] = val;
        out0[(size_t)i * Dc + o] = feats[(size_t)i * Dc + o] * val;
      }
    }
  }
}

// ---------------------------------------------------------------------------
// Flash-style attention, fp32. One block = 32 q-rows of one (b,h).
// q,k,v: [B,H,S,HD]; mask: [B,1,S,S]; ctx out: [B,S,D] (heads merged)
// ---------------------------------------------------------------------------
#define QB 32
#define KB 64

__global__ __launch_bounds__(256)
void attn_kernel(const float* __restrict__ q, const float* __restrict__ k,
                 const float* __restrict__ v, const float* __restrict__ mask,
                 float* __restrict__ ctx)
{
  __shared__ float Qs[QB][HDc];       // 8 KB (broadcast reads only)
  __shared__ float Ks[KB][HDc + 1];   // padded: kills stride-64 conflicts
  __shared__ float Vs[KB][HDc + 4];   // padded to 68 for aligned float4 reads
  __shared__ float Ps[QB][HDc + 1];
  __shared__ float m_s[QB], l_s[QB], c_s[QB], tmax_s[QB], tsum_s[QB];

  const int tid  = threadIdx.x;
  const int lane = tid & 63;
  const int wave = tid >> 6;           // 0..3
  const int nqb  = Sc / QB;            // 64
  const int head = blockIdx.x / nqb;   // b*H + h
  const int q0   = (blockIdx.x % nqb) * QB;
  const int b    = head / Hc;
  const int h    = head % Hc;

  const float* qbase = q + ((size_t)head * Sc + q0) * HDc;
  const float* kbase = k + (size_t)head * Sc * HDc;
  const float* vbase = v + (size_t)head * Sc * HDc;
  const float* mbase = mask + ((size_t)b * Sc + q0) * Sc;

  // load Q tile (2048 consecutive floats)
#pragma unroll
  for (int j = 0; j < 8; ++j) {
    int e = tid + 256 * j;
    Qs[e >> 6][e & 63] = qbase[e];
  }
  if (tid < QB) { m_s[tid] = -1e30f; l_s[tid] = 0.f; }

  float o_acc[8] = {0.f};
  const int r_own = tid >> 3;        // PV row owned by this thread
  const int c0    = (tid & 7) * 8;   // PV col base

  for (int kt = 0; kt < Sc / KB; ++kt) {
    const int k0 = kt * KB;
    __syncthreads();  // protect Ks/Vs/Ps from previous iteration's readers
    // load K,V tiles (4096 consecutive floats each)
#pragma unroll
    for (int j = 0; j < 16; ++j) {
      int e = tid + 256 * j;
      int r = e >> 6, c = e & 63;
      Ks[r][c] = kbase[(size_t)k0 * HDc + e];
      Vs[r][c] = vbase[(size_t)k0 * HDc + e];
    }
    __syncthreads();

    // scores: thread handles rows r = wave + 4*j (wave-uniform), col = lane
    float dot[8] = {0.f};
#pragma unroll
    for (int d = 0; d < HDc; ++d) {
      float kd = Ks[lane][d];
#pragma unroll
      for (int j = 0; j < 8; ++j) dot[j] += Qs[wave + 4 * j][d] * kd;
    }
#pragma unroll
    for (int j = 0; j < 8; ++j) {
      int r = wave + 4 * j;
      dot[j] += mbase[(size_t)r * Sc + k0 + lane];
    }

    // per-row tile max via 64-lane shuffle reduce
#pragma unroll
    for (int j = 0; j < 8; ++j) {
      float vm = dot[j];
      for (int off = 32; off >= 1; off >>= 1) vm = fmaxf(vm, __shfl_xor(vm, off));
      if (lane == 0) tmax_s[wave + 4 * j] = vm;
    }
    __syncthreads();
    if (tid < QB) {
      float mo = m_s[tid];
      float mn = fmaxf(mo, tmax_s[tid]);
      c_s[tid] = __expf(mo - mn);
      m_s[tid] = mn;
    }
    __syncthreads();

    // P = exp(s - m), row sums
#pragma unroll
    for (int j = 0; j < 8; ++j) {
      int r = wave + 4 * j;
      float p = __expf(dot[j] - m_s[r]);
      Ps[r][lane] = p;
      float ps = p;
      for (int off = 32; off >= 1; off >>= 1) ps += __shfl_xor(ps, off);
      if (lane == 0) tsum_s[r] = ps;
    }
    __syncthreads();
    if (tid < QB) l_s[tid] = l_s[tid] * c_s[tid] + tsum_s[tid];

    // PV accumulate (each thread: one row, 8 contiguous cols)
    {
      float corr = c_s[r_own];
#pragma unroll
      for (int x = 0; x < 8; ++x) o_acc[x] *= corr;
#pragma unroll
      for (int kk = 0; kk < KB; ++kk) {
        float p = Ps[r_own][kk];
        const float4* vrow = reinterpret_cast<const float4*>(&Vs[kk][c0]);
        float4 v0 = vrow[0], v1 = vrow[1];
        o_acc[0] += p * v0.x; o_acc[1] += p * v0.y;
        o_acc[2] += p * v0.z; o_acc[3] += p * v0.w;
        o_acc[4] += p * v1.x; o_acc[5] += p * v1.y;
        o_acc[6] += p * v1.z; o_acc[7] += p * v1.w;
      }
    }
  }
  __syncthreads();

  const float inv_l = 1.0f / l_s[r_own];
  float4 w0 = make_float4(o_acc[0] * inv_l, o_acc[1] * inv_l,
                          o_acc[2] * inv_l, o_acc[3] * inv_l);
  float4 w1 = make_float4(o_acc[4] * inv_l, o_acc[5] * inv_l,
                          o_acc[6] * inv_l, o_acc[7] * inv_l);
  float* dst = ctx + ((size_t)b * Sc + (q0 + r_own)) * Dc + h * HDc + c0;
  reinterpret_cast<float4*>(dst)[0] = w0;
  reinterpret_cast<float4*>(dst)[1] = w1;
}

// ---------------------------------------------------------------------------
extern "C" void kernel_launch(void* const* d_in, const int* in_sizes, int n_in,
                              void* d_out, int out_size, void* d_ws, size_t ws_size,
                              hipStream_t stream) {
  const float* feats = (const float*)d_in[0];
  const float* mask  = (const float*)d_in[1];
  const float* wq    = (const float*)d_in[2];
  const float* bq    = (const float*)d_in[3];
  const float* wk    = (const float*)d_in[4];
  const float* bk    = (const float*)d_in[5];
  const float* wv    = (const float*)d_in[6];
  const float* bv    = (const float*)d_in[7];
  const float* wo    = (const float*)d_in[8];
  const float* bo    = (const float*)d_in[9];

  float* ws  = (float*)d_ws;
  float* q   = ws;                 // [B,H,S,HD] 4,194,304 floats
  float* k   = ws + 4194304;
  float* v   = ws + 8388608;
  float* ctx = ws + 12582912;      // [B,S,D]

  float* out   = (float*)d_out;    // 4,194,304 floats
  float* gated = out + 4194304;

  dim3 gg(NROWS / 64, Dc / 64);    // (64, 16)
  gemm_kernel<<<gg, 256, 0, stream>>>(feats, wq, bq, 0.125f, q, nullptr, nullptr, 0);
  gemm_kernel<<<gg, 256, 0, stream>>>(feats, wk, bk, 1.0f,   k, nullptr, nullptr, 0);
  gemm_kernel<<<gg, 256, 0, stream>>>(feats, wv, bv, 1.0f,   v, nullptr, nullptr, 0);

  attn_kernel<<<Bc * Hc * (Sc / QB), 256, 0, stream>>>(q, k, v, mask, ctx);

  gemm_kernel<<<gg, 256, 0, stream>>>(ctx, wo, bo, 1.0f, out, gated, feats, 1);
}

// Round 3
// 926.624 us; speedup vs baseline: 4.5601x; 4.5601x over previous
//
#include <hip/hip_runtime.h>
#include <math.h>

#define Bc 2
#define Sc 2048
#define Dc 1024
#define Hc 16
#define HDc 64
#define NROWS 4096  // B*S

typedef __attribute__((ext_vector_type(8))) short bf16x8;
typedef __attribute__((ext_vector_type(4))) float f32x4;

__device__ __forceinline__ unsigned short f2bf(float f) {
  union { float f; unsigned int u; } x; x.f = f;
  unsigned int r = (x.u + 0x7FFFu + ((x.u >> 16) & 1u)) >> 16;
  return (unsigned short)r;
}

// ---------------------------------------------------------------------------
// GEMM: C = (A @ W^T + bias) * alpha   (fp32 compute)
//   mode 0: bf16 head-split write -> outb as [B,H,S,HD]
//   mode 1: bf16 head-split TRANSPOSED -> outb as [B,H,HD,S]   (for V)
//   mode 2: fp32: out1 = val (gated); out0 = feats*val (out)
// ---------------------------------------------------------------------------
__global__ __launch_bounds__(256)
void gemm_kernel(const float* __restrict__ A, const float* __restrict__ W,
                 const float* __restrict__ bias, float alpha,
                 unsigned short* __restrict__ outb,
                 float* __restrict__ out0, float* __restrict__ out1,
                 const float* __restrict__ feats, int mode)
{
  __shared__ float As[64][17];
  __shared__ float Ws[64][17];
  const int tid = threadIdx.x;
  const int tx = tid & 15, ty = tid >> 4;
  const int row0 = blockIdx.x * 64, col0 = blockIdx.y * 64;
  float acc[4][4] = {{0.f}};

  for (int k0 = 0; k0 < Dc; k0 += 16) {
#pragma unroll
    for (int j = 0; j < 4; ++j) {
      int e = tid + 256 * j;
      int r = e >> 4, c = e & 15;
      As[r][c] = A[(size_t)(row0 + r) * Dc + k0 + c];
      Ws[r][c] = W[(size_t)(col0 + r) * Dc + k0 + c];
    }
    __syncthreads();
#pragma unroll
    for (int kk = 0; kk < 16; ++kk) {
      float a[4], w[4];
#pragma unroll
      for (int m = 0; m < 4; ++m) a[m] = As[ty * 4 + m][kk];
#pragma unroll
      for (int n = 0; n < 4; ++n) w[n] = Ws[tx * 4 + n][kk];
#pragma unroll
      for (int m = 0; m < 4; ++m)
#pragma unroll
        for (int n = 0; n < 4; ++n) acc[m][n] += a[m] * w[n];
    }
    __syncthreads();
  }

#pragma unroll
  for (int m = 0; m < 4; ++m) {
#pragma unroll
    for (int n = 0; n < 4; ++n) {
      int i = row0 + ty * 4 + m;
      int o = col0 + tx * 4 + n;
      float val = (acc[m][n] + bias[o]) * alpha;
      int b = i >> 11, s = i & (Sc - 1);
      int h = o >> 6, hd = o & 63;
      if (mode == 0) {
        outb[(((size_t)b * Hc + h) * Sc + s) * HDc + hd] = f2bf(val);
      } else if (mode == 1) {
        outb[(((size_t)b * Hc + h) * HDc + hd) * Sc + s] = f2bf(val);
      } else {
        out1[(size_t)i * Dc + o] = val;
        out0[(size_t)i * Dc + o] = feats[(size_t)i * Dc + o] * val;
      }
    }
  }
}

// ---------------------------------------------------------------------------
// Flash attention, bf16 MFMA. Block = 4 waves; wave owns 16 q-rows (QB=64).
// q,k: bf16 [B,H,S,HD]; vt: bf16 [B,H,HD,S]; mask fp32 [B,1,S,S];
// ctx out fp32 [B,S,D] (heads merged).
// ---------------------------------------------------------------------------
#define QB 64
#define KB 64

__global__ __launch_bounds__(256)
void attn_mfma(const unsigned short* __restrict__ q,
               const unsigned short* __restrict__ k,
               const unsigned short* __restrict__ vt,
               const float* __restrict__ mask,
               float* __restrict__ ctx)
{
  __shared__ unsigned short Ks[KB][72];      // [k-row][head-dim], +8 pad
  __shared__ unsigned short Vs[HDc][72];     // V^T tile: [d][k-col], +8 pad
  __shared__ unsigned short Ps[4][16][72];   // per-wave P tile

  const int tid  = threadIdx.x;
  const int lane = tid & 63;
  const int wave = tid >> 6;
  const int l15  = lane & 15;
  const int l4   = lane >> 4;

  const int nqb  = Sc / QB;            // 32
  const int head = blockIdx.x / nqb;   // b*H + h
  const int q0   = (blockIdx.x % nqb) * QB;
  const int b    = head / Hc;
  const int h    = head % Hc;

  const unsigned short* qbase  = q  + ((size_t)head * Sc + q0 + wave * 16) * HDc;
  const unsigned short* kbase  = k  + (size_t)head * Sc * HDc;
  const unsigned short* vtbase = vt + (size_t)head * HDc * Sc;
  const float*          mbase  = mask + ((size_t)b * Sc + q0 + wave * 16) * Sc;

  // Q A-frags: row = l15, k-dim = l4*8 + 32*f + i  (16B contiguous loads)
  bf16x8 qf[2];
#pragma unroll
  for (int f = 0; f < 2; ++f)
    qf[f] = *reinterpret_cast<const bf16x8*>(
        qbase + (size_t)l15 * HDc + l4 * 8 + 32 * f);

  f32x4 O[4];
#pragma unroll
  for (int dt = 0; dt < 4; ++dt) O[dt] = f32x4{0.f, 0.f, 0.f, 0.f};
  float m_r[4], l_r[4];
#pragma unroll
  for (int r = 0; r < 4; ++r) { m_r[r] = -3e38f; l_r[r] = 0.f; }

  for (int kt = 0; kt < Sc / KB; ++kt) {
    const int k0 = kt * KB;
    __syncthreads();
    // stage K tile [KB][64] and V^T tile [64][KB] (16B chunks)
#pragma unroll
    for (int p = 0; p < 2; ++p) {
      int c = tid + 256 * p;
      int r = c >> 3, col = (c & 7) * 8;
      uint4 kd = *reinterpret_cast<const uint4*>(
          kbase + (size_t)(k0 + r) * HDc + col);
      *reinterpret_cast<uint4*>(&Ks[r][col]) = kd;
      uint4 vd = *reinterpret_cast<const uint4*>(
          vtbase + (size_t)r * Sc + k0 + col);
      *reinterpret_cast<uint4*>(&Vs[r][col]) = vd;
    }
    __syncthreads();

    // S = Q K^T  (4 N-tiles of 16 k-cols, K=64 via 2 MFMAs)
    f32x4 s[4];
#pragma unroll
    for (int nt = 0; nt < 4; ++nt) {
      f32x4 acc = f32x4{0.f, 0.f, 0.f, 0.f};
      acc = __builtin_amdgcn_mfma_f32_16x16x32_bf16(
          qf[0], *reinterpret_cast<const bf16x8*>(&Ks[16 * nt + l15][l4 * 8]),
          acc, 0, 0, 0);
      acc = __builtin_amdgcn_mfma_f32_16x16x32_bf16(
          qf[1], *reinterpret_cast<const bf16x8*>(&Ks[16 * nt + l15][l4 * 8 + 32]),
          acc, 0, 0, 0);
      s[nt] = acc;
    }
    // + mask (D-layout: row = l4*4+reg, col = l15 + 16*nt)
#pragma unroll
    for (int reg = 0; reg < 4; ++reg) {
      const float* mr = mbase + (size_t)(l4 * 4 + reg) * Sc + k0 + l15;
#pragma unroll
      for (int nt = 0; nt < 4; ++nt) s[nt][reg] += mr[16 * nt];
    }

    // online softmax: row reduce across the 16 lanes of each D-layout group
    float cc[4];
#pragma unroll
    for (int reg = 0; reg < 4; ++reg) {
      float vm = fmaxf(fmaxf(s[0][reg], s[1][reg]), fmaxf(s[2][reg], s[3][reg]));
      vm = fmaxf(vm, __shfl_xor(vm, 1));
      vm = fmaxf(vm, __shfl_xor(vm, 2));
      vm = fmaxf(vm, __shfl_xor(vm, 4));
      vm = fmaxf(vm, __shfl_xor(vm, 8));
      float mn = fmaxf(m_r[reg], vm);
      cc[reg] = __expf(m_r[reg] - mn);
      m_r[reg] = mn;
    }
#pragma unroll
    for (int reg = 0; reg < 4; ++reg) {
      float ps = 0.f;
#pragma unroll
      for (int nt = 0; nt < 4; ++nt) {
        float p = __expf(s[nt][reg] - m_r[reg]);
        ps += p;
        Ps[wave][l4 * 4 + reg][l15 + 16 * nt] = f2bf(p);
      }
      ps += __shfl_xor(ps, 1);
      ps += __shfl_xor(ps, 2);
      ps += __shfl_xor(ps, 4);
      ps += __shfl_xor(ps, 8);
      l_r[reg] = l_r[reg] * cc[reg] + ps;
    }
    // rescale O
#pragma unroll
    for (int dt = 0; dt < 4; ++dt)
#pragma unroll
      for (int reg = 0; reg < 4; ++reg) O[dt][reg] *= cc[reg];

    asm volatile("" ::: "memory");  // keep Ps writes ordered before reads

    // O += P V   (A-frag of P from LDS; B-frag of V from V^T tile)
    bf16x8 pa0 = *reinterpret_cast<const bf16x8*>(&Ps[wave][l15][l4 * 8]);
    bf16x8 pa1 = *reinterpret_cast<const bf16x8*>(&Ps[wave][l15][l4 * 8 + 32]);
#pragma unroll
    for (int dt = 0; dt < 4; ++dt) {
      O[dt] = __builtin_amdgcn_mfma_f32_16x16x32_bf16(
          pa0, *reinterpret_cast<const bf16x8*>(&Vs[16 * dt + l15][l4 * 8]),
          O[dt], 0, 0, 0);
      O[dt] = __builtin_amdgcn_mfma_f32_16x16x32_bf16(
          pa1, *reinterpret_cast<const bf16x8*>(&Vs[16 * dt + l15][l4 * 8 + 32]),
          O[dt], 0, 0, 0);
    }
  }

  // epilogue: O / l, write ctx fp32 [B,S,D]
  float inv[4];
#pragma unroll
  for (int reg = 0; reg < 4; ++reg) inv[reg] = 1.0f / l_r[reg];
#pragma unroll
  for (int dt = 0; dt < 4; ++dt)
#pragma unroll
    for (int reg = 0; reg < 4; ++reg) {
      int row = q0 + wave * 16 + l4 * 4 + reg;
      ctx[((size_t)b * Sc + row) * Dc + h * HDc + l15 + 16 * dt] =
          O[dt][reg] * inv[reg];
    }
}

// ---------------------------------------------------------------------------
extern "C" void kernel_launch(void* const* d_in, const int* in_sizes, int n_in,
                              void* d_out, int out_size, void* d_ws, size_t ws_size,
                              hipStream_t stream) {
  const float* feats = (const float*)d_in[0];
  const float* mask  = (const float*)d_in[1];
  const float* wq    = (const float*)d_in[2];
  const float* bq    = (const float*)d_in[3];
  const float* wk    = (const float*)d_in[4];
  const float* bk    = (const float*)d_in[5];
  const float* wv    = (const float*)d_in[6];
  const float* bv    = (const float*)d_in[7];
  const float* wo    = (const float*)d_in[8];
  const float* bo    = (const float*)d_in[9];

  char* ws = (char*)d_ws;
  unsigned short* qb  = (unsigned short*)(ws);
  unsigned short* kb  = (unsigned short*)(ws + (((size_t)8)  << 20));
  unsigned short* vtb = (unsigned short*)(ws + (((size_t)16) << 20));
  float*          ctx = (float*)        (ws + (((size_t)24) << 20));

  float* out   = (float*)d_out;
  float* gated = out + 4194304;

  dim3 gg(NROWS / 64, Dc / 64);
  gemm_kernel<<<gg, 256, 0, stream>>>(feats, wq, bq, 0.125f, qb,  nullptr, nullptr, nullptr, 0);
  gemm_kernel<<<gg, 256, 0, stream>>>(feats, wk, bk, 1.0f,   kb,  nullptr, nullptr, nullptr, 0);
  gemm_kernel<<<gg, 256, 0, stream>>>(feats, wv, bv, 1.0f,   vtb, nullptr, nullptr, nullptr, 1);

  attn_mfma<<<Bc * Hc * (Sc / QB), 256, 0, stream>>>(qb, kb, vtb, mask, ctx);

  gemm_kernel<<<gg, 256, 0, stream>>>(ctx, wo, bo, 1.0f, nullptr, out, gated, feats, 2);
}

// Round 4
// 360.435 us; speedup vs baseline: 11.7234x; 2.5708x over previous
//
#include <hip/hip_runtime.h>
#include <math.h>

#define Bc 2
#define Sc 2048
#define Dc 1024
#define Hc 16
#define HDc 64
#define NROWS 4096  // B*S

typedef __attribute__((ext_vector_type(8))) short bf16x8;
typedef __attribute__((ext_vector_type(8))) _Float16 f16x8;
typedef __attribute__((ext_vector_type(4))) _Float16 f16x4;
typedef __attribute__((ext_vector_type(4))) float f32x4;

__device__ __forceinline__ unsigned short f2bf(float f) {
  union { float f; unsigned int u; } x; x.f = f;
  unsigned int r = (x.u + 0x7FFFu + ((x.u >> 16) & 1u)) >> 16;
  return (unsigned short)r;
}

// ---------------------------------------------------------------------------
// fp32 -> f16 hi + f16 lo  (x = hi + lo, lo = x - (float)hi)
// ---------------------------------------------------------------------------
__global__ __launch_bounds__(256)
void split_kernel(const float* __restrict__ src, _Float16* __restrict__ hi,
                  _Float16* __restrict__ lo, int n4)
{
  int i = blockIdx.x * 256 + threadIdx.x;
  if (i >= n4) return;
  float4 v = reinterpret_cast<const float4*>(src)[i];
  f16x4 h, l;
  h[0] = (_Float16)v.x; l[0] = (_Float16)(v.x - (float)h[0]);
  h[1] = (_Float16)v.y; l[1] = (_Float16)(v.y - (float)h[1]);
  h[2] = (_Float16)v.z; l[2] = (_Float16)(v.z - (float)h[2]);
  h[3] = (_Float16)v.w; l[3] = (_Float16)(v.w - (float)h[3]);
  reinterpret_cast<f16x4*>(hi)[i] = h;
  reinterpret_cast<f16x4*>(lo)[i] = l;
}

// ---------------------------------------------------------------------------
// Split-precision MFMA GEMM: C = (A@W^T + bias)*alpha via f16 hi/lo (3 MFMA).
//   A: [M,K=1024] rows over K;  W: [N,K=1024] rows over K. grid (M/128,N/128).
//   mode 0: bf16 head-split -> outb [B,H,S,HD]           (rows=B*S, cols=D)
//   mode 1: bf16, rows are the o-index -> outb [B,H,HD,S] (rows=D, cols=B*S)
//           (bias indexed by ROW)
//   mode 2: fp32: out1 = val (gated); out0 = feats*val (out)
// ---------------------------------------------------------------------------
__global__ __launch_bounds__(256, 3)
void gemm_mfma(const _Float16* __restrict__ Ah, const _Float16* __restrict__ Al,
               const _Float16* __restrict__ Wh, const _Float16* __restrict__ Wl,
               const float* __restrict__ bias, float alpha,
               unsigned short* __restrict__ outb,
               float* __restrict__ out0, float* __restrict__ out1,
               const float* __restrict__ feats, int mode)
{
  __shared__ _Float16 Ash[128][40];   // +8 pad: 80B pitch -> free 2-way alias
  __shared__ _Float16 Asl[128][40];
  __shared__ _Float16 Wsh[128][40];
  __shared__ _Float16 Wsl[128][40];

  const int tid  = threadIdx.x;
  const int lane = tid & 63, wid = tid >> 6;
  const int l15  = lane & 15, l4 = lane >> 4;
  const int wr   = wid >> 1, wc = wid & 1;     // wave tile 64x64
  const int arow0 = blockIdx.x * 128;
  const int wrow0 = blockIdx.y * 128;

  f32x4 acc[4][4];
#pragma unroll
  for (int m = 0; m < 4; ++m)
#pragma unroll
    for (int n = 0; n < 4; ++n) acc[m][n] = f32x4{0.f, 0.f, 0.f, 0.f};

  for (int k0 = 0; k0 < Dc; k0 += 32) {
    __syncthreads();
#pragma unroll
    for (int p = 0; p < 2; ++p) {
      int e = tid + 256 * p;
      int r = e >> 2, c8 = (e & 3) * 8;
      size_t ao = (size_t)(arow0 + r) * Dc + k0 + c8;
      size_t wo = (size_t)(wrow0 + r) * Dc + k0 + c8;
      uint4 a0 = *reinterpret_cast<const uint4*>(Ah + ao);
      uint4 a1 = *reinterpret_cast<const uint4*>(Al + ao);
      uint4 w0 = *reinterpret_cast<const uint4*>(Wh + wo);
      uint4 w1 = *reinterpret_cast<const uint4*>(Wl + wo);
      *reinterpret_cast<uint4*>(&Ash[r][c8]) = a0;
      *reinterpret_cast<uint4*>(&Asl[r][c8]) = a1;
      *reinterpret_cast<uint4*>(&Wsh[r][c8]) = w0;
      *reinterpret_cast<uint4*>(&Wsl[r][c8]) = w1;
    }
    __syncthreads();

    f16x8 bh[4], bl[4];
#pragma unroll
    for (int n = 0; n < 4; ++n) {
      bh[n] = *reinterpret_cast<const f16x8*>(&Wsh[wc * 64 + n * 16 + l15][l4 * 8]);
      bl[n] = *reinterpret_cast<const f16x8*>(&Wsl[wc * 64 + n * 16 + l15][l4 * 8]);
    }
#pragma unroll
    for (int m = 0; m < 4; ++m) {
      f16x8 ah = *reinterpret_cast<const f16x8*>(&Ash[wr * 64 + m * 16 + l15][l4 * 8]);
      f16x8 al = *reinterpret_cast<const f16x8*>(&Asl[wr * 64 + m * 16 + l15][l4 * 8]);
#pragma unroll
      for (int n = 0; n < 4; ++n) {
        acc[m][n] = __builtin_amdgcn_mfma_f32_16x16x32_f16(ah, bh[n], acc[m][n], 0, 0, 0);
        acc[m][n] = __builtin_amdgcn_mfma_f32_16x16x32_f16(ah, bl[n], acc[m][n], 0, 0, 0);
        acc[m][n] = __builtin_amdgcn_mfma_f32_16x16x32_f16(al, bh[n], acc[m][n], 0, 0, 0);
      }
    }
  }

  // epilogue: C/D layout col = l15, row = l4*4 + reg
#pragma unroll
  for (int m = 0; m < 4; ++m) {
#pragma unroll
    for (int n = 0; n < 4; ++n) {
#pragma unroll
      for (int reg = 0; reg < 4; ++reg) {
        int r = arow0 + wr * 64 + m * 16 + l4 * 4 + reg;
        int c = wrow0 + wc * 64 + n * 16 + l15;
        float bval = (mode == 1) ? bias[r] : bias[c];
        float val = (acc[m][n][reg] + bval) * alpha;
        if (mode == 0) {
          int b = r >> 11, s = r & (Sc - 1), h = c >> 6, hd = c & 63;
          outb[(((size_t)b * Hc + h) * Sc + s) * HDc + hd] = f2bf(val);
        } else if (mode == 1) {
          int h = r >> 6, hd = r & 63, b = c >> 11, s = c & (Sc - 1);
          outb[(((size_t)b * Hc + h) * HDc + hd) * Sc + s] = f2bf(val);
        } else {
          out1[(size_t)r * Dc + c] = val;
          out0[(size_t)r * Dc + c] = feats[(size_t)r * Dc + c] * val;
        }
      }
    }
  }
}

// ---------------------------------------------------------------------------
// Flash attention, bf16 MFMA. Block = 4 waves; wave owns 16 q-rows (QB=64).
// q,k: bf16 [B,H,S,HD]; vt: bf16 [B,H,HD,S]; mask fp32 [B,1,S,S];
// ctx out: f16 hi/lo [B,S,D] (heads merged).
// ---------------------------------------------------------------------------
#define QB 64
#define KB 64

__global__ __launch_bounds__(256)
void attn_mfma(const unsigned short* __restrict__ q,
               const unsigned short* __restrict__ k,
               const unsigned short* __restrict__ vt,
               const float* __restrict__ mask,
               _Float16* __restrict__ ctxh, _Float16* __restrict__ ctxl)
{
  __shared__ unsigned short Ks[KB][72];      // [k-row][head-dim], +8 pad
  __shared__ unsigned short Vs[HDc][72];     // V^T tile: [d][k-col], +8 pad
  __shared__ unsigned short Ps[4][16][72];   // per-wave P tile

  const int tid  = threadIdx.x;
  const int lane = tid & 63;
  const int wave = tid >> 6;
  const int l15  = lane & 15;
  const int l4   = lane >> 4;

  const int nqb  = Sc / QB;            // 32
  const int head = blockIdx.x / nqb;   // b*H + h
  const int q0   = (blockIdx.x % nqb) * QB;
  const int b    = head / Hc;
  const int h    = head % Hc;

  const unsigned short* qbase  = q  + ((size_t)head * Sc + q0 + wave * 16) * HDc;
  const unsigned short* kbase  = k  + (size_t)head * Sc * HDc;
  const unsigned short* vtbase = vt + (size_t)head * HDc * Sc;
  const float*          mbase  = mask + ((size_t)b * Sc + q0 + wave * 16) * Sc;

  bf16x8 qf[2];
#pragma unroll
  for (int f = 0; f < 2; ++f)
    qf[f] = *reinterpret_cast<const bf16x8*>(
        qbase + (size_t)l15 * HDc + l4 * 8 + 32 * f);

  f32x4 O[4];
#pragma unroll
  for (int dt = 0; dt < 4; ++dt) O[dt] = f32x4{0.f, 0.f, 0.f, 0.f};
  float m_r[4], l_r[4];
#pragma unroll
  for (int r = 0; r < 4; ++r) { m_r[r] = -3e38f; l_r[r] = 0.f; }

  for (int kt = 0; kt < Sc / KB; ++kt) {
    const int k0 = kt * KB;
    __syncthreads();
#pragma unroll
    for (int p = 0; p < 2; ++p) {
      int c = tid + 256 * p;
      int r = c >> 3, col = (c & 7) * 8;
      uint4 kd = *reinterpret_cast<const uint4*>(
          kbase + (size_t)(k0 + r) * HDc + col);
      *reinterpret_cast<uint4*>(&Ks[r][col]) = kd;
      uint4 vd = *reinterpret_cast<const uint4*>(
          vtbase + (size_t)r * Sc + k0 + col);
      *reinterpret_cast<uint4*>(&Vs[r][col]) = vd;
    }
    __syncthreads();

    f32x4 s[4];
#pragma unroll
    for (int nt = 0; nt < 4; ++nt) {
      f32x4 acc = f32x4{0.f, 0.f, 0.f, 0.f};
      acc = __builtin_amdgcn_mfma_f32_16x16x32_bf16(
          qf[0], *reinterpret_cast<const bf16x8*>(&Ks[16 * nt + l15][l4 * 8]),
          acc, 0, 0, 0);
      acc = __builtin_amdgcn_mfma_f32_16x16x32_bf16(
          qf[1], *reinterpret_cast<const bf16x8*>(&Ks[16 * nt + l15][l4 * 8 + 32]),
          acc, 0, 0, 0);
      s[nt] = acc;
    }
#pragma unroll
    for (int reg = 0; reg < 4; ++reg) {
      const float* mr = mbase + (size_t)(l4 * 4 + reg) * Sc + k0 + l15;
#pragma unroll
      for (int nt = 0; nt < 4; ++nt) s[nt][reg] += mr[16 * nt];
    }

    float cc[4];
#pragma unroll
    for (int reg = 0; reg < 4; ++reg) {
      float vm = fmaxf(fmaxf(s[0][reg], s[1][reg]), fmaxf(s[2][reg], s[3][reg]));
      vm = fmaxf(vm, __shfl_xor(vm, 1));
      vm = fmaxf(vm, __shfl_xor(vm, 2));
      vm = fmaxf(vm, __shfl_xor(vm, 4));
      vm = fmaxf(vm, __shfl_xor(vm, 8));
      float mn = fmaxf(m_r[reg], vm);
      cc[reg] = __expf(m_r[reg] - mn);
      m_r[reg] = mn;
    }
#pragma unroll
    for (int reg = 0; reg < 4; ++reg) {
      float ps = 0.f;
#pragma unroll
      for (int nt = 0; nt < 4; ++nt) {
        float p = __expf(s[nt][reg] - m_r[reg]);
        ps += p;
        Ps[wave][l4 * 4 + reg][l15 + 16 * nt] = f2bf(p);
      }
      ps += __shfl_xor(ps, 1);
      ps += __shfl_xor(ps, 2);
      ps += __shfl_xor(ps, 4);
      ps += __shfl_xor(ps, 8);
      l_r[reg] = l_r[reg] * cc[reg] + ps;
    }
#pragma unroll
    for (int dt = 0; dt < 4; ++dt)
#pragma unroll
      for (int reg = 0; reg < 4; ++reg) O[dt][reg] *= cc[reg];

    asm volatile("" ::: "memory");

    bf16x8 pa0 = *reinterpret_cast<const bf16x8*>(&Ps[wave][l15][l4 * 8]);
    bf16x8 pa1 = *reinterpret_cast<const bf16x8*>(&Ps[wave][l15][l4 * 8 + 32]);
#pragma unroll
    for (int dt = 0; dt < 4; ++dt) {
      O[dt] = __builtin_amdgcn_mfma_f32_16x16x32_bf16(
          pa0, *reinterpret_cast<const bf16x8*>(&Vs[16 * dt + l15][l4 * 8]),
          O[dt], 0, 0, 0);
      O[dt] = __builtin_amdgcn_mfma_f32_16x16x32_bf16(
          pa1, *reinterpret_cast<const bf16x8*>(&Vs[16 * dt + l15][l4 * 8 + 32]),
          O[dt], 0, 0, 0);
    }
  }

  float inv[4];
#pragma unroll
  for (int reg = 0; reg < 4; ++reg) inv[reg] = 1.0f / l_r[reg];
#pragma unroll
  for (int dt = 0; dt < 4; ++dt)
#pragma unroll
    for (int reg = 0; reg < 4; ++reg) {
      int row = q0 + wave * 16 + l4 * 4 + reg;
      size_t addr = ((size_t)b * Sc + row) * Dc + h * HDc + l15 + 16 * dt;
      float val = O[dt][reg] * inv[reg];
      _Float16 hh = (_Float16)val;
      ctxh[addr] = hh;
      ctxl[addr] = (_Float16)(val - (float)hh);
    }
}

// ---------------------------------------------------------------------------
extern "C" void kernel_launch(void* const* d_in, const int* in_sizes, int n_in,
                              void* d_out, int out_size, void* d_ws, size_t ws_size,
                              hipStream_t stream) {
  const float* feats = (const float*)d_in[0];
  const float* mask  = (const float*)d_in[1];
  const float* wq    = (const float*)d_in[2];
  const float* bq    = (const float*)d_in[3];
  const float* wk    = (const float*)d_in[4];
  const float* bk    = (const float*)d_in[5];
  const float* wv    = (const float*)d_in[6];
  const float* bv    = (const float*)d_in[7];
  const float* wo    = (const float*)d_in[8];
  const float* bo    = (const float*)d_in[9];

  char* ws = (char*)d_ws;
  const size_t MB = (size_t)1 << 20;
  _Float16* fh  = (_Float16*)(ws);             // 8 MB
  _Float16* fl  = (_Float16*)(ws + 8  * MB);   // 8 MB
  _Float16* wqh = (_Float16*)(ws + 16 * MB);
  _Float16* wql = (_Float16*)(ws + 18 * MB);
  _Float16* wkh = (_Float16*)(ws + 20 * MB);
  _Float16* wkl = (_Float16*)(ws + 22 * MB);
  _Float16* wvh = (_Float16*)(ws + 24 * MB);
  _Float16* wvl = (_Float16*)(ws + 26 * MB);
  _Float16* woh = (_Float16*)(ws + 28 * MB);
  _Float16* wol = (_Float16*)(ws + 30 * MB);
  unsigned short* qb  = (unsigned short*)(ws + 32 * MB);
  unsigned short* kb  = (unsigned short*)(ws + 40 * MB);
  unsigned short* vtb = (unsigned short*)(ws + 48 * MB);
  _Float16* ctxh = (_Float16*)(ws + 56 * MB);
  _Float16* ctxl = (_Float16*)(ws + 64 * MB);  // end: 72 MB

  float* out   = (float*)d_out;
  float* gated = out + 4194304;

  // precision splits
  split_kernel<<<4096, 256, 0, stream>>>(feats, fh, fl, 1048576);
  split_kernel<<<1024, 256, 0, stream>>>(wq, wqh, wql, 262144);
  split_kernel<<<1024, 256, 0, stream>>>(wk, wkh, wkl, 262144);
  split_kernel<<<1024, 256, 0, stream>>>(wv, wvh, wvl, 262144);
  split_kernel<<<1024, 256, 0, stream>>>(wo, woh, wol, 262144);

  dim3 gqk(NROWS / 128, Dc / 128);   // (32, 8)
  dim3 gvt(Dc / 128, NROWS / 128);   // (8, 32)
  gemm_mfma<<<gqk, 256, 0, stream>>>(fh, fl, wqh, wql, bq, 0.125f, qb,
                                     nullptr, nullptr, nullptr, 0);
  gemm_mfma<<<gqk, 256, 0, stream>>>(fh, fl, wkh, wkl, bk, 1.0f, kb,
                                     nullptr, nullptr, nullptr, 0);
  // V^T = wv @ feats^T  (rows = o-index, cols = token)
  gemm_mfma<<<gvt, 256, 0, stream>>>(wvh, wvl, fh, fl, bv, 1.0f, vtb,
                                     nullptr, nullptr, nullptr, 1);

  attn_mfma<<<Bc * Hc * (Sc / QB), 256, 0, stream>>>(qb, kb, vtb, mask, ctxh, ctxl);

  gemm_mfma<<<gqk, 256, 0, stream>>>(ctxh, ctxl, woh, wol, bo, 1.0f, nullptr,
                                     out, gated, feats, 2);
}